// Round 1
// baseline (576.697 us; speedup 1.0000x reference)
//
#include <hip/hip_runtime.h>
#include <hip/hip_bf16.h>

typedef _Float16 half8 __attribute__((ext_vector_type(8)));
typedef float floatx4 __attribute__((ext_vector_type(4)));

// ---------------------------------------------------------------------------
// Swizzled LDS layout for 64x256 fp16 activation tiles (no padding, 64 KiB for
// two buffers => 2 blocks/CU). Chunk = 8 halfs (16B). Rotating chunk by row
// spreads the 16-rows-same-k ds_read_b128 A-fragment pattern across all 32
// banks (<=2-way aliasing, free per m136).
// ---------------------------------------------------------------------------
__device__ __forceinline__ int swz(int row, int col) {
    int chunk = col >> 3;
    int inner = col & 7;
    return row * 256 + (((chunk + row) & 31) << 3) + inner;
}

// ---------------------------------------------------------------------------
// Weight pre-pack: fp32 (K,N) row-major -> fp16 MFMA B-fragment order.
// Per 32x16 (KxN) tile: 64 lanes x 8 halfs; lane L holds B[k0+(L>>4)*8+j][n0+(L&15)].
// Tiles laid out linearly: dst[tile*512 + lane*8 + j]. K/N padded with zeros:
//   L1: 39->64 x 256 | L2-4: 256x256 | L5: 295->320 x 256 | L6-8: 256x256 | L9: 256 x 4->16
// Total 968 tiles = 495616 halfs = 991232 B in d_ws.
// ---------------------------------------------------------------------------
__global__ void pack_w(const float* __restrict__ w1, const float* __restrict__ w2,
                       const float* __restrict__ w3, const float* __restrict__ w4,
                       const float* __restrict__ w5, const float* __restrict__ w6,
                       const float* __restrict__ w7, const float* __restrict__ w8,
                       const float* __restrict__ w9, _Float16* __restrict__ dst) {
    const int tileStart[10] = {0, 32, 160, 288, 416, 576, 704, 832, 960, 968};
    const int Ks[9] = {39, 256, 256, 256, 295, 256, 256, 256, 256};
    const int Ns[9] = {256, 256, 256, 256, 256, 256, 256, 256, 4};
    const int Tn[9] = {16, 16, 16, 16, 16, 16, 16, 16, 1};
    const float* ws[9] = {w1, w2, w3, w4, w5, w6, w7, w8, w9};

    int g = blockIdx.x * blockDim.x + threadIdx.x;
    int tile = g >> 6, lane = g & 63;
    if (tile >= 968) return;
    int layer = 0;
    while (tile >= tileStart[layer + 1]) layer++;
    int t = tile - tileStart[layer];
    int tn = Tn[layer];
    int k0t = t / tn, n0t = t - k0t * tn;
    int kk0 = k0t * 32 + (lane >> 4) * 8;
    int nn = n0t * 16 + (lane & 15);
    const float* w = ws[layer];
    int K = Ks[layer], Nn = Ns[layer];
    _Float16 v[8];
#pragma unroll
    for (int j = 0; j < 8; j++) {
        int kk = kk0 + j;
        float f = (kk < K && nn < Nn) ? w[kk * Nn + nn] : 0.f;
        v[j] = (_Float16)f;
    }
    *(half8*)(dst + (size_t)tile * 512 + lane * 8) = *(half8*)v;
}

// ---------------------------------------------------------------------------
// One fused layer: C(64x256) = relu(A(64xK) @ W(Kx256) + b), LDS->LDS.
// 4 waves, wave w owns cols [64w, 64w+64): 4 row-tiles x 4 col-tiles of
// 16x16x32 f16 MFMA. B fragments double-buffered straight from L2 (prepacked).
// AMODE: 0 = A from LDS; 1 = LDS + last 2 K-steps from x register frags
// (layer-5 skip concat); 2 = A entirely from x register frags (layer 1).
// ---------------------------------------------------------------------------
template <int KSTEPS, int AMODE, bool RELU>
__device__ __forceinline__ void layerf(const _Float16* __restrict__ abuf,
                                       const half8 (&xf)[2][4],
                                       const half8* __restrict__ wq,
                                       const float* __restrict__ bias,
                                       _Float16* __restrict__ obuf,
                                       int lane, int wave) {
    const int l15 = lane & 15, lq = lane >> 4;
    const int nw = wave * 4;
    floatx4 acc[4][4] = {};
    half8 bcur[4], bnxt[4];
#pragma unroll
    for (int n = 0; n < 4; n++) bcur[n] = wq[(nw + n) * 64 + lane];
#pragma unroll
    for (int k0 = 0; k0 < KSTEPS; k0++) {
        if (k0 + 1 < KSTEPS) {
#pragma unroll
            for (int n = 0; n < 4; n++)
                bnxt[n] = wq[((k0 + 1) * 16 + nw + n) * 64 + lane];
        }
#pragma unroll
        for (int m = 0; m < 4; m++) {
            half8 a;
            if (AMODE == 2) {
                a = xf[k0][m];
            } else if (AMODE == 1 && k0 >= KSTEPS - 2) {
                a = xf[k0 - (KSTEPS - 2)][m];
            } else {
                a = *(const half8*)(abuf + swz(m * 16 + l15, k0 * 32 + lq * 8));
            }
#pragma unroll
            for (int n = 0; n < 4; n++)
                acc[m][n] = __builtin_amdgcn_mfma_f32_16x16x32_f16(a, bcur[n], acc[m][n], 0, 0, 0);
        }
        if (k0 + 1 < KSTEPS) {
#pragma unroll
            for (int n = 0; n < 4; n++) bcur[n] = bnxt[n];
        }
    }
    // Epilogue: bias + relu + fp16 convert, write C-layout (col=lane&15,
    // row=(lane>>4)*4+r) into swizzled LDS.
#pragma unroll
    for (int n = 0; n < 4; n++) {
        float bv = bias[wave * 64 + n * 16 + l15];
#pragma unroll
        for (int m = 0; m < 4; m++) {
#pragma unroll
            for (int r = 0; r < 4; r++) {
                float v = acc[m][n][r] + bv;
                if (RELU) v = v > 0.f ? v : 0.f;
                obuf[swz(m * 16 + lq * 4 + r, wave * 64 + n * 16 + l15)] = (_Float16)v;
            }
        }
    }
}

// Layer 9: 256 -> 4 (padded to 16 cols of zeros). Wave w handles rows 16w..16w+15.
__device__ __forceinline__ void layer9f(const _Float16* __restrict__ abuf,
                                        const half8* __restrict__ wq,
                                        const float* __restrict__ b9,
                                        float* __restrict__ out, long r0,
                                        int lane, int wave) {
    const int l15 = lane & 15, lq = lane >> 4;
    floatx4 acc = {0.f, 0.f, 0.f, 0.f};
#pragma unroll
    for (int k0 = 0; k0 < 8; k0++) {
        half8 a = *(const half8*)(abuf + swz(wave * 16 + l15, k0 * 32 + lq * 8));
        half8 b = wq[k0 * 64 + lane];
        acc = __builtin_amdgcn_mfma_f32_16x16x32_f16(a, b, acc, 0, 0, 0);
    }
    if (l15 < 4) {
        float bv = b9[l15];
#pragma unroll
        for (int r = 0; r < 4; r++)
            out[(r0 + wave * 16 + lq * 4 + r) * 4 + l15] = acc[r] + bv;
    }
}

__global__ __launch_bounds__(256, 2) void mlp_fused(
    const float* __restrict__ x, const _Float16* __restrict__ wpk,
    const float* __restrict__ b1, const float* __restrict__ b2,
    const float* __restrict__ b3, const float* __restrict__ b4,
    const float* __restrict__ b5, const float* __restrict__ b6,
    const float* __restrict__ b7, const float* __restrict__ b8,
    const float* __restrict__ b9, float* __restrict__ out) {
    __shared__ _Float16 lds[2 * 64 * 256];  // 64 KiB exactly -> 2 blocks/CU
    _Float16* buf0 = lds;
    _Float16* buf1 = lds + 64 * 256;
    const int tid = threadIdx.x;
    const int lane = tid & 63, wave = tid >> 6;
    const long r0 = (long)blockIdx.x * 64;

    // ---- Stage x (64 rows x 39 cols, zero-padded to 64) into buf0, 8-chunk
    // rotation swizzle, then pull A-fragments into registers (shared by L1+L5).
    for (int i = tid; i < 64 * 64 / 2; i += 256) ((unsigned*)buf0)[i] = 0u;
    __syncthreads();
    for (int i = tid; i < 64 * 39; i += 256) {
        int row = i / 39, col = i - row * 39;
        float v = x[r0 * 39 + i];  // fully coalesced: contiguous 2496 floats
        buf0[row * 64 + ((((col >> 3) + row) & 7) << 3) + (col & 7)] = (_Float16)v;
    }
    __syncthreads();
    half8 xf[2][4];
    {
        const int l15 = lane & 15, lq = lane >> 4;
#pragma unroll
        for (int m = 0; m < 4; m++) {
            int row = m * 16 + l15;
#pragma unroll
            for (int ks = 0; ks < 2; ks++) {
                int chunk = ks * 4 + lq;
                xf[ks][m] = *(const half8*)(buf0 + row * 64 + (((chunk + row) & 7) << 3));
            }
        }
    }
    __syncthreads();

    // Packed weight bases (half8 units; tile = 64 half8)
    const half8* wp = (const half8*)wpk;
    const half8* w1q = wp + (size_t)0 * 64;
    const half8* w2q = wp + (size_t)32 * 64;
    const half8* w3q = wp + (size_t)160 * 64;
    const half8* w4q = wp + (size_t)288 * 64;
    const half8* w5q = wp + (size_t)416 * 64;
    const half8* w6q = wp + (size_t)576 * 64;
    const half8* w7q = wp + (size_t)704 * 64;
    const half8* w8q = wp + (size_t)832 * 64;
    const half8* w9q = wp + (size_t)960 * 64;

    layerf<2, 2, true>(buf0, xf, w1q, b1, buf1, lane, wave);   // x -> buf1
    __syncthreads();
    layerf<8, 0, true>(buf1, xf, w2q, b2, buf0, lane, wave);
    __syncthreads();
    layerf<8, 0, true>(buf0, xf, w3q, b3, buf1, lane, wave);
    __syncthreads();
    layerf<8, 0, true>(buf1, xf, w4q, b4, buf0, lane, wave);
    __syncthreads();
    layerf<10, 1, true>(buf0, xf, w5q, b5, buf1, lane, wave);  // [h|x] skip concat
    __syncthreads();
    layerf<8, 0, true>(buf1, xf, w6q, b6, buf0, lane, wave);
    __syncthreads();
    layerf<8, 0, true>(buf0, xf, w7q, b7, buf1, lane, wave);
    __syncthreads();
    layerf<8, 0, true>(buf1, xf, w8q, b8, buf0, lane, wave);
    __syncthreads();
    layer9f(buf0, w9q, b9, out, r0, lane, wave);
}

extern "C" void kernel_launch(void* const* d_in, const int* in_sizes, int n_in,
                              void* d_out, int out_size, void* d_ws, size_t ws_size,
                              hipStream_t stream) {
    const float* x = (const float*)d_in[0];
    const float* w[9];
    const float* b[9];
    for (int i = 0; i < 9; i++) {
        w[i] = (const float*)d_in[1 + 2 * i];
        b[i] = (const float*)d_in[2 + 2 * i];
    }
    _Float16* wpk = (_Float16*)d_ws;  // needs 991232 B

    pack_w<<<242, 256, 0, stream>>>(w[0], w[1], w[2], w[3], w[4], w[5], w[6], w[7], w[8], wpk);
    mlp_fused<<<262144 / 64, 256, 0, stream>>>(x, wpk, b[0], b[1], b[2], b[3], b[4],
                                               b[5], b[6], b[7], b[8], (float*)d_out);
}

// Round 2
// 565.435 us; speedup vs baseline: 1.0199x; 1.0199x over previous
//
#include <hip/hip_runtime.h>
#include <hip/hip_bf16.h>

typedef _Float16 half8 __attribute__((ext_vector_type(8)));
typedef float floatx16 __attribute__((ext_vector_type(16)));

// ---------------------------------------------------------------------------
// Swizzled LDS layouts. Chunk = 8 halfs (16B); rotating chunk by row keeps
// ds_read_b128 column-pattern reads at the bank-BW floor (<=4-way on 32-row
// reads = 1024B/instr minimum anyway) and b128 alignment is preserved.
// act buffers: 64 rows x 256 cols. x buffer: 64 rows x 64 cols (8 KiB).
// ---------------------------------------------------------------------------
__device__ __forceinline__ int swz(int row, int col) {
    return row * 256 + ((((col >> 3) + row) & 31) << 3) + (col & 7);
}
__device__ __forceinline__ int xswz(int row, int col) {
    return row * 64 + ((((col >> 3) + row) & 7) << 3) + (col & 7);
}

// ---------------------------------------------------------------------------
// Weight pre-pack: fp32 (K,N) row-major -> fp16 MFMA B-fragment order for
// 32x32x16: tile = 16k x 32n; lane L holds B[kt*16 + 8*(L>>5) + j][nt*32 + (L&31)].
// K/N zero-padded: L1 39->48, L5 295->304, L9 N 4->32.
// Tile starts: {0,24,152,280,408,560,688,816,944}, total 960 tiles = 983040 B.
// ---------------------------------------------------------------------------
__global__ void pack_w32(const float* __restrict__ w1, const float* __restrict__ w2,
                         const float* __restrict__ w3, const float* __restrict__ w4,
                         const float* __restrict__ w5, const float* __restrict__ w6,
                         const float* __restrict__ w7, const float* __restrict__ w8,
                         const float* __restrict__ w9, _Float16* __restrict__ dst) {
    const int tileStart[10] = {0, 24, 152, 280, 408, 560, 688, 816, 944, 960};
    const int Ks[9] = {39, 256, 256, 256, 295, 256, 256, 256, 256};
    const int Ns[9] = {256, 256, 256, 256, 256, 256, 256, 256, 4};
    const int Tn[9] = {8, 8, 8, 8, 8, 8, 8, 8, 1};
    const float* ws[9] = {w1, w2, w3, w4, w5, w6, w7, w8, w9};

    int g = blockIdx.x * blockDim.x + threadIdx.x;
    int tile = g >> 6, lane = g & 63;
    if (tile >= 960) return;
    int layer = 0;
    while (tile >= tileStart[layer + 1]) layer++;
    int t = tile - tileStart[layer];
    int tn = Tn[layer];
    int kt = t / tn, nt = t - kt * tn;
    int k0 = kt * 16 + (lane >> 5) * 8;
    int n = nt * 32 + (lane & 31);
    const float* w = ws[layer];
    int K = Ks[layer], N = Ns[layer];
    _Float16 v[8];
#pragma unroll
    for (int j = 0; j < 8; j++) {
        int k = k0 + j;
        v[j] = (k < K && n < N) ? (_Float16)w[k * N + n] : (_Float16)0.f;
    }
    *(half8*)(dst + (size_t)tile * 512 + lane * 8) = *(half8*)v;
}

// ---------------------------------------------------------------------------
// One fused layer: C(64x256) = relu(A(64xK) @ W + b), LDS->LDS.
// 4 waves; wave owns 64 cols = 2 n-tiles of 32. 2 m-tiles of 32.
// 32x32x16 f16 MFMA, depth-2 B prefetch ring straight from L2 (prepacked).
// AMODE 0: A from act buffer. 1: ks>=KS0 reads x buffer (layer-5 skip).
// 2: A entirely from x buffer (layer 1).
// ---------------------------------------------------------------------------
template <int KT, int AMODE, int KS0>
__device__ __forceinline__ void layerf32(const _Float16* __restrict__ abuf,
                                         const _Float16* __restrict__ xbuf,
                                         const half8* __restrict__ wq,
                                         const float* __restrict__ bias,
                                         _Float16* __restrict__ obuf,
                                         int lane, int wave) {
    const int l31 = lane & 31, lhi = lane >> 5;
    floatx16 acc[2][2] = {};
    half8 bfr[3][2];
#pragma unroll
    for (int s = 0; s < 2; s++) {
        if (s < KT) {
#pragma unroll
            for (int n = 0; n < 2; n++)
                bfr[s][n] = wq[(s * 8 + wave * 2 + n) * 64 + lane];
        }
    }
#pragma unroll
    for (int ks = 0; ks < KT; ks++) {
        if (ks + 2 < KT) {
#pragma unroll
            for (int n = 0; n < 2; n++)
                bfr[(ks + 2) % 3][n] = wq[((ks + 2) * 8 + wave * 2 + n) * 64 + lane];
        }
        half8 a[2];
#pragma unroll
        for (int m = 0; m < 2; m++) {
            int row = m * 32 + l31;
            if (AMODE == 2) {
                a[m] = *(const half8*)(xbuf + xswz(row, ks * 16 + lhi * 8));
            } else if (AMODE == 1 && ks >= KS0) {
                a[m] = *(const half8*)(xbuf + xswz(row, (ks - KS0) * 16 + lhi * 8));
            } else {
                a[m] = *(const half8*)(abuf + swz(row, ks * 16 + lhi * 8));
            }
        }
#pragma unroll
        for (int m = 0; m < 2; m++)
#pragma unroll
            for (int n = 0; n < 2; n++)
                acc[m][n] = __builtin_amdgcn_mfma_f32_32x32x16_f16(a[m], bfr[ks % 3][n],
                                                                   acc[m][n], 0, 0, 0);
    }
    // Epilogue: bias + relu + fp16, C layout: col=lane&31,
    // row=(reg&3)+8*(reg>>2)+4*(lane>>5).
#pragma unroll
    for (int n = 0; n < 2; n++) {
        int col = wave * 64 + n * 32 + l31;
        float bv = bias[col];
#pragma unroll
        for (int m = 0; m < 2; m++) {
#pragma unroll
            for (int r = 0; r < 16; r++) {
                int row = m * 32 + lhi * 4 + (r & 3) + ((r >> 2) << 3);
                float v = acc[m][n][r] + bv;
                v = v > 0.f ? v : 0.f;
                obuf[swz(row, col)] = (_Float16)v;
            }
        }
    }
}

// Layer 9: 256 -> 4 (N padded to 32). Waves 0,1 each take one 32-row m-tile.
__device__ __forceinline__ void layer9f(const _Float16* __restrict__ abuf,
                                        const half8* __restrict__ wq,
                                        const float* __restrict__ b9,
                                        float* __restrict__ out, long r0,
                                        int lane, int wave) {
    if (wave >= 2) return;
    const int l31 = lane & 31, lhi = lane >> 5;
    floatx16 acc = {};
#pragma unroll
    for (int ks = 0; ks < 16; ks++) {
        half8 a = *(const half8*)(abuf + swz(wave * 32 + l31, ks * 16 + lhi * 8));
        half8 b = wq[ks * 64 + lane];
        acc = __builtin_amdgcn_mfma_f32_32x32x16_f16(a, b, acc, 0, 0, 0);
    }
    if (l31 < 4) {
        float bv = b9[l31];
#pragma unroll
        for (int r = 0; r < 16; r++) {
            int row = wave * 32 + lhi * 4 + (r & 3) + ((r >> 2) << 3);
            out[(r0 + row) * 4 + l31] = acc[r] + bv;
        }
    }
}

__global__ __launch_bounds__(256, 2) void mlp_fused(
    const float* __restrict__ x, const _Float16* __restrict__ wpk,
    const float* __restrict__ b1, const float* __restrict__ b2,
    const float* __restrict__ b3, const float* __restrict__ b4,
    const float* __restrict__ b5, const float* __restrict__ b6,
    const float* __restrict__ b7, const float* __restrict__ b8,
    const float* __restrict__ b9, float* __restrict__ out) {
    // 2 x 32 KiB activation ping-pong + 8 KiB persistent x tile = 72 KiB
    // -> 2 blocks/CU; VGPRs up to 256 are free at this occupancy.
    __shared__ _Float16 lds[2 * 64 * 256 + 64 * 64];
    _Float16* buf0 = lds;
    _Float16* buf1 = lds + 64 * 256;
    _Float16* xbuf = lds + 2 * 64 * 256;
    const int tid = threadIdx.x;
    const int lane = tid & 63, wave = tid >> 6;
    const long r0 = (long)blockIdx.x * 64;

    // Stage x: zero the pad cols (39..63) and fill cols 0..38 — disjoint, one barrier.
    for (int i = tid; i < 64 * 25; i += 256) {
        int row = i / 25, col = 39 + (i - row * 25);
        xbuf[xswz(row, col)] = (_Float16)0.f;
    }
    for (int i = tid; i < 64 * 39; i += 256) {
        int row = i / 39, col = i - row * 39;
        xbuf[xswz(row, col)] = (_Float16)x[r0 * 39 + i];  // contiguous 2496 floats
    }
    __syncthreads();

    const half8* wp = (const half8*)wpk;  // tile = 64 half8
    const half8* w1q = wp + (size_t)0 * 64;
    const half8* w2q = wp + (size_t)24 * 64;
    const half8* w3q = wp + (size_t)152 * 64;
    const half8* w4q = wp + (size_t)280 * 64;
    const half8* w5q = wp + (size_t)408 * 64;
    const half8* w6q = wp + (size_t)560 * 64;
    const half8* w7q = wp + (size_t)688 * 64;
    const half8* w8q = wp + (size_t)816 * 64;
    const half8* w9q = wp + (size_t)944 * 64;

    layerf32<3, 2, 0>(xbuf, xbuf, w1q, b1, buf1, lane, wave);
    __syncthreads();
    layerf32<16, 0, 0>(buf1, xbuf, w2q, b2, buf0, lane, wave);
    __syncthreads();
    layerf32<16, 0, 0>(buf0, xbuf, w3q, b3, buf1, lane, wave);
    __syncthreads();
    layerf32<16, 0, 0>(buf1, xbuf, w4q, b4, buf0, lane, wave);
    __syncthreads();
    layerf32<19, 1, 16>(buf0, xbuf, w5q, b5, buf1, lane, wave);  // [h|x] skip
    __syncthreads();
    layerf32<16, 0, 0>(buf1, xbuf, w6q, b6, buf0, lane, wave);
    __syncthreads();
    layerf32<16, 0, 0>(buf0, xbuf, w7q, b7, buf1, lane, wave);
    __syncthreads();
    layerf32<16, 0, 0>(buf1, xbuf, w8q, b8, buf0, lane, wave);
    __syncthreads();
    layer9f(buf0, w9q, b9, out, r0, lane, wave);
}

extern "C" void kernel_launch(void* const* d_in, const int* in_sizes, int n_in,
                              void* d_out, int out_size, void* d_ws, size_t ws_size,
                              hipStream_t stream) {
    const float* x = (const float*)d_in[0];
    const float* w[9];
    const float* b[9];
    for (int i = 0; i < 9; i++) {
        w[i] = (const float*)d_in[1 + 2 * i];
        b[i] = (const float*)d_in[2 + 2 * i];
    }
    _Float16* wpk = (_Float16*)d_ws;  // 983040 B

    pack_w32<<<240, 256, 0, stream>>>(w[0], w[1], w[2], w[3], w[4], w[5], w[6], w[7], w[8], wpk);
    mlp_fused<<<262144 / 64, 256, 0, stream>>>(x, wpk, b[0], b[1], b[2], b[3], b[4],
                                               b[5], b[6], b[7], b[8], (float*)d_out);
}

// Round 3
// 404.115 us; speedup vs baseline: 1.4271x; 1.3992x over previous
//
#include <hip/hip_runtime.h>
#include <hip/hip_bf16.h>

typedef _Float16 half8 __attribute__((ext_vector_type(8)));
typedef float floatx16 __attribute__((ext_vector_type(16)));

// ---------------------------------------------------------------------------
// Swizzled LDS layouts (chunk = 8 halfs = 16B, rotated by row).
// act buffers: 64x256 fp16 (32 KiB). x buffer: 64x64 fp16 (8 KiB).
// ---------------------------------------------------------------------------
__device__ __forceinline__ int swz(int row, int col) {
    return row * 256 + ((((col >> 3) + row) & 31) << 3) + (col & 7);
}
__device__ __forceinline__ int xswz(int row, int col) {
    return row * 64 + ((((col >> 3) + row) & 7) << 3) + (col & 7);
}

// ---------------------------------------------------------------------------
// Weight pre-pack: fp32 (K,N) row-major -> fp16 B-fragment order for
// v_mfma_f32_32x32x16_f16: tile = 16k x 32n; lane L holds
// B[kt*16 + 8*(L>>5) + j][nt*32 + (L&31)], j=0..7.
// K zero-padded to EVEN k-step counts: L1 39->64 (KT=4), L5 295->320 (KT=20),
// others 256 (KT=16). L9 N 4->32. Tile starts (in 1KB tiles):
// {0,32,160,288,416,576,704,832,960}, total 976 tiles = 999424 B in d_ws.
// ---------------------------------------------------------------------------
__global__ void pack_w32(const float* __restrict__ w1, const float* __restrict__ w2,
                         const float* __restrict__ w3, const float* __restrict__ w4,
                         const float* __restrict__ w5, const float* __restrict__ w6,
                         const float* __restrict__ w7, const float* __restrict__ w8,
                         const float* __restrict__ w9, _Float16* __restrict__ dst) {
    const int tileStart[10] = {0, 32, 160, 288, 416, 576, 704, 832, 960, 976};
    const int Ks[9] = {39, 256, 256, 256, 295, 256, 256, 256, 256};
    const int Ns[9] = {256, 256, 256, 256, 256, 256, 256, 256, 4};
    const int Tn[9] = {8, 8, 8, 8, 8, 8, 8, 8, 1};
    const float* ws[9] = {w1, w2, w3, w4, w5, w6, w7, w8, w9};

    int g = blockIdx.x * blockDim.x + threadIdx.x;
    int tile = g >> 6, lane = g & 63;
    if (tile >= 976) return;
    int layer = 0;
    while (tile >= tileStart[layer + 1]) layer++;
    int t = tile - tileStart[layer];
    int tn = Tn[layer];
    int kt = t / tn, nt = t - kt * tn;
    int k0 = kt * 16 + (lane >> 5) * 8;
    int n = nt * 32 + (lane & 31);
    const float* w = ws[layer];
    int K = Ks[layer], N = Ns[layer];
    _Float16 v[8];
#pragma unroll
    for (int j = 0; j < 8; j++) {
        int k = k0 + j;
        v[j] = (k < K && n < N) ? (_Float16)w[k * N + n] : (_Float16)0.f;
    }
    *(half8*)(dst + (size_t)tile * 512 + lane * 8) = *(half8*)v;
}

// A-fragment read for k-step ks. AMODE 0: act buffer. 1: ks>=KS0 from x buffer
// (layer-5 skip concat). 2: entirely from x buffer (layer 1).
template <int AMODE, int KS0>
__device__ __forceinline__ void loadA(const _Float16* __restrict__ abuf,
                                      const _Float16* __restrict__ xbuf,
                                      int ks, int l31, int lhi,
                                      half8& a0, half8& a1) {
    if (AMODE == 2 || (AMODE == 1 && ks >= KS0)) {
        int c = ((AMODE == 2) ? ks : (ks - KS0)) * 16 + lhi * 8;
        a0 = *(const half8*)(xbuf + xswz(l31, c));
        a1 = *(const half8*)(xbuf + xswz(32 + l31, c));
    } else {
        int c = ks * 16 + lhi * 8;
        a0 = *(const half8*)(abuf + swz(l31, c));
        a1 = *(const half8*)(abuf + swz(32 + l31, c));
    }
}

// ---------------------------------------------------------------------------
// One fused layer: C(64x256) = relu(A(64xK) @ W + b), LDS->LDS.
// 4 waves; wave owns 64 cols (2 n-tiles of 32), 2 m-tiles of 32 rows.
// KEY CHANGE vs R2: the k-loop is a REAL loop (#pragma unroll 1), 2 k-steps
// per iteration, two-stream depth-2 register prefetch (bA/bB live one full
// iteration = 2 k-steps ~ covers L2 latency). This bounds the scheduler's
// load-hoisting window — the full unroll in R1/R2 blew VGPR pressure and
// caused ~300 MB of scratch spill traffic (the real bottleneck at 966 GB/s).
// ---------------------------------------------------------------------------
template <int KT, int AMODE, int KS0>
__device__ __forceinline__ void layerf32(const _Float16* __restrict__ abuf,
                                         const _Float16* __restrict__ xbuf,
                                         const half8* __restrict__ wq,
                                         const float* __restrict__ bias,
                                         _Float16* __restrict__ obuf,
                                         int lane, int wave) {
    static_assert((KT & 1) == 0 && KT >= 4, "KT must be even >= 4");
    const int l31 = lane & 31, lhi = lane >> 5;
    // b-frag element for (kstep ks, n-tile n): wq[(ks*8 + wave*2 + n)*64 + lane]
    const half8* wl = wq + (wave * 2) * 64 + lane;
    float bv0 = bias[wave * 64 + l31];        // prefetched before the k-loop
    float bv1 = bias[wave * 64 + 32 + l31];
    floatx16 acc00 = {}, acc01 = {}, acc10 = {}, acc11 = {};
    half8 bA0 = wl[0], bA1 = wl[64];
    half8 bB0 = wl[512], bB1 = wl[512 + 64];
#pragma unroll 1
    for (int ks = 0; ks < KT - 2; ks += 2) {
        half8 nA0 = wl[(ks + 2) * 512], nA1 = wl[(ks + 2) * 512 + 64];
        half8 nB0 = wl[(ks + 3) * 512], nB1 = wl[(ks + 3) * 512 + 64];
        half8 a0, a1;
        loadA<AMODE, KS0>(abuf, xbuf, ks, l31, lhi, a0, a1);
        acc00 = __builtin_amdgcn_mfma_f32_32x32x16_f16(a0, bA0, acc00, 0, 0, 0);
        acc01 = __builtin_amdgcn_mfma_f32_32x32x16_f16(a0, bA1, acc01, 0, 0, 0);
        acc10 = __builtin_amdgcn_mfma_f32_32x32x16_f16(a1, bA0, acc10, 0, 0, 0);
        acc11 = __builtin_amdgcn_mfma_f32_32x32x16_f16(a1, bA1, acc11, 0, 0, 0);
        loadA<AMODE, KS0>(abuf, xbuf, ks + 1, l31, lhi, a0, a1);
        acc00 = __builtin_amdgcn_mfma_f32_32x32x16_f16(a0, bB0, acc00, 0, 0, 0);
        acc01 = __builtin_amdgcn_mfma_f32_32x32x16_f16(a0, bB1, acc01, 0, 0, 0);
        acc10 = __builtin_amdgcn_mfma_f32_32x32x16_f16(a1, bB0, acc10, 0, 0, 0);
        acc11 = __builtin_amdgcn_mfma_f32_32x32x16_f16(a1, bB1, acc11, 0, 0, 0);
        bA0 = nA0; bA1 = nA1; bB0 = nB0; bB1 = nB1;
    }
    {   // tail: k-steps KT-2 (bA) and KT-1 (bB), no prefetch
        half8 a0, a1;
        loadA<AMODE, KS0>(abuf, xbuf, KT - 2, l31, lhi, a0, a1);
        acc00 = __builtin_amdgcn_mfma_f32_32x32x16_f16(a0, bA0, acc00, 0, 0, 0);
        acc01 = __builtin_amdgcn_mfma_f32_32x32x16_f16(a0, bA1, acc01, 0, 0, 0);
        acc10 = __builtin_amdgcn_mfma_f32_32x32x16_f16(a1, bA0, acc10, 0, 0, 0);
        acc11 = __builtin_amdgcn_mfma_f32_32x32x16_f16(a1, bA1, acc11, 0, 0, 0);
        loadA<AMODE, KS0>(abuf, xbuf, KT - 1, l31, lhi, a0, a1);
        acc00 = __builtin_amdgcn_mfma_f32_32x32x16_f16(a0, bB0, acc00, 0, 0, 0);
        acc01 = __builtin_amdgcn_mfma_f32_32x32x16_f16(a0, bB1, acc01, 0, 0, 0);
        acc10 = __builtin_amdgcn_mfma_f32_32x32x16_f16(a1, bB0, acc10, 0, 0, 0);
        acc11 = __builtin_amdgcn_mfma_f32_32x32x16_f16(a1, bB1, acc11, 0, 0, 0);
    }
    // Epilogue: bias + relu + fp16. C layout: col=lane&31,
    // row=(reg&3)+8*(reg>>2)+4*(lane>>5).
    floatx16 accs[2][2] = {{acc00, acc01}, {acc10, acc11}};
#pragma unroll
    for (int n = 0; n < 2; n++) {
        float bv = n ? bv1 : bv0;
        int col = wave * 64 + n * 32 + l31;
#pragma unroll
        for (int m = 0; m < 2; m++) {
#pragma unroll
            for (int r = 0; r < 16; r++) {
                int row = m * 32 + lhi * 4 + (r & 3) + ((r >> 2) << 3);
                float v = accs[m][n][r] + bv;
                v = v > 0.f ? v : 0.f;
                obuf[swz(row, col)] = (_Float16)v;
            }
        }
    }
}

// Layer 9: 256 -> 4 (N padded to 32). Waves 0,1 take one 32-row m-tile each.
__device__ __forceinline__ void layer9f(const _Float16* __restrict__ abuf,
                                        const half8* __restrict__ wq,
                                        const float* __restrict__ b9,
                                        float* __restrict__ out, long r0,
                                        int lane, int wave) {
    if (wave >= 2) return;
    const int l31 = lane & 31, lhi = lane >> 5;
    floatx16 acc = {};
    half8 bc = wq[lane];
#pragma unroll 1
    for (int ks = 0; ks < 15; ks++) {
        half8 bn = wq[(ks + 1) * 64 + lane];
        half8 a = *(const half8*)(abuf + swz(wave * 32 + l31, ks * 16 + lhi * 8));
        acc = __builtin_amdgcn_mfma_f32_32x32x16_f16(a, bc, acc, 0, 0, 0);
        bc = bn;
    }
    half8 a = *(const half8*)(abuf + swz(wave * 32 + l31, 15 * 16 + lhi * 8));
    acc = __builtin_amdgcn_mfma_f32_32x32x16_f16(a, bc, acc, 0, 0, 0);
    if (l31 < 4) {
        float bv = b9[l31];
#pragma unroll
        for (int r = 0; r < 16; r++) {
            int row = wave * 32 + lhi * 4 + (r & 3) + ((r >> 2) << 3);
            out[(r0 + row) * 4 + l31] = acc[r] + bv;
        }
    }
}

__global__ __launch_bounds__(256, 2) void mlp_fused(
    const float* __restrict__ x, const _Float16* __restrict__ wpk,
    const float* __restrict__ b1, const float* __restrict__ b2,
    const float* __restrict__ b3, const float* __restrict__ b4,
    const float* __restrict__ b5, const float* __restrict__ b6,
    const float* __restrict__ b7, const float* __restrict__ b8,
    const float* __restrict__ b9, float* __restrict__ out) {
    // 2 x 32 KiB activation ping-pong + 8 KiB persistent x tile = 72 KiB
    // -> 2 blocks/CU (LDS-capped); VGPRs up to 256 free at this occupancy.
    __shared__ _Float16 lds[2 * 64 * 256 + 64 * 64];
    _Float16* buf0 = lds;
    _Float16* buf1 = lds + 64 * 256;
    _Float16* xbuf = lds + 2 * 64 * 256;
    const int tid = threadIdx.x;
    const int lane = tid & 63, wave = tid >> 6;
    const long r0 = (long)blockIdx.x * 64;

    // Stage x: zero pad cols (39..63) and fill cols 0..38 — disjoint, one barrier.
    for (int i = tid; i < 64 * 25; i += 256) {
        int row = i / 25, col = 39 + (i - row * 25);
        xbuf[xswz(row, col)] = (_Float16)0.f;
    }
    for (int i = tid; i < 64 * 39; i += 256) {
        int row = i / 39, col = i - row * 39;
        xbuf[xswz(row, col)] = (_Float16)x[r0 * 39 + i];  // contiguous 2496 floats
    }
    __syncthreads();

    const half8* wp = (const half8*)wpk;  // tile = 64 half8
    const half8* w1q = wp + (size_t)0 * 64;
    const half8* w2q = wp + (size_t)32 * 64;
    const half8* w3q = wp + (size_t)160 * 64;
    const half8* w4q = wp + (size_t)288 * 64;
    const half8* w5q = wp + (size_t)416 * 64;
    const half8* w6q = wp + (size_t)576 * 64;
    const half8* w7q = wp + (size_t)704 * 64;
    const half8* w8q = wp + (size_t)832 * 64;
    const half8* w9q = wp + (size_t)960 * 64;

    layerf32<4, 2, 0>(xbuf, xbuf, w1q, b1, buf1, lane, wave);
    __syncthreads();
    layerf32<16, 0, 0>(buf1, xbuf, w2q, b2, buf0, lane, wave);
    __syncthreads();
    layerf32<16, 0, 0>(buf0, xbuf, w3q, b3, buf1, lane, wave);
    __syncthreads();
    layerf32<16, 0, 0>(buf1, xbuf, w4q, b4, buf0, lane, wave);
    __syncthreads();
    layerf32<20, 1, 16>(buf0, xbuf, w5q, b5, buf1, lane, wave);  // [h|x] skip
    __syncthreads();
    layerf32<16, 0, 0>(buf1, xbuf, w6q, b6, buf0, lane, wave);
    __syncthreads();
    layerf32<16, 0, 0>(buf0, xbuf, w7q, b7, buf1, lane, wave);
    __syncthreads();
    layerf32<16, 0, 0>(buf1, xbuf, w8q, b8, buf0, lane, wave);
    __syncthreads();
    layer9f(buf0, w9q, b9, out, r0, lane, wave);
}

extern "C" void kernel_launch(void* const* d_in, const int* in_sizes, int n_in,
                              void* d_out, int out_size, void* d_ws, size_t ws_size,
                              hipStream_t stream) {
    const float* x = (const float*)d_in[0];
    const float* w[9];
    const float* b[9];
    for (int i = 0; i < 9; i++) {
        w[i] = (const float*)d_in[1 + 2 * i];
        b[i] = (const float*)d_in[2 + 2 * i];
    }
    _Float16* wpk = (_Float16*)d_ws;  // 999424 B

    pack_w32<<<244, 256, 0, stream>>>(w[0], w[1], w[2], w[3], w[4], w[5], w[6], w[7], w[8], wpk);
    mlp_fused<<<262144 / 64, 256, 0, stream>>>(x, wpk, b[0], b[1], b[2], b[3], b[4],
                                               b[5], b[6], b[7], b[8], (float*)d_out);
}